// Round 13
// baseline (159.662 us; speedup 1.0000x reference)
//
#include <hip/hip_runtime.h>
#include <hip/hip_bf16.h>
#include <math.h>

#define NPIX 2304
#define CCH  128
#define NH   4
#define HC   32
#define NCL  16
#define KSPLIT 8
#define KEYS 288
#define NSTEP 9
#define QSCALE 0.25503489f               // log2(e)/sqrt(32)
#define PPT  16

typedef __attribute__((ext_vector_type(8))) short short8;
typedef __attribute__((ext_vector_type(4))) short short4v;
typedef __attribute__((ext_vector_type(4))) float f32x4;

#if __has_builtin(__builtin_amdgcn_exp2f)
#define EXP2(x) __builtin_amdgcn_exp2f(x)
#else
#define EXP2(x) __expf((x) * 0.6931471805599453f)
#endif

static __device__ __forceinline__ short f2bf(float x) {
    __hip_bfloat16 b = __float2bfloat16(x);
    return *reinterpret_cast<short*>(&b);
}

// ---------------- Kernel 1: q/k/v projections + centersA + weight pack ---------
// r12-verified: r7 proj body + blockIdx.y==3 slice packing the 4 MLP matrices
// to [out][in] bf16 (kills the pack_w dispatch).
__global__ void __launch_bounds__(256) proj_kernel(
        const float* __restrict__ xq, const float* __restrict__ xk,
        const float* __restrict__ xv, const int* __restrict__ labels,
        const float* __restrict__ wq, const float* __restrict__ bq,
        const float* __restrict__ wk, const float* __restrict__ bk,
        const float* __restrict__ wv, const float* __restrict__ bv,
        const float* __restrict__ w1a, const float* __restrict__ w1b,
        const float* __restrict__ w2a, const float* __restrict__ w2b,
        short* __restrict__ qbf, short* __restrict__ kbf,
        float* __restrict__ vbuf, short* __restrict__ vbfT,
        float* __restrict__ cpart, float* __restrict__ denpart,
        short* __restrict__ t1a, short* __restrict__ t1b,
        short* __restrict__ t2a, short* __restrict__ t2b) {
    __shared__ float xsP[CCH * PPT];          // 8 KB
    __shared__ float ls2[2 * NCL * CCH];      // 16 KB
    __shared__ float smls[32];
    const int which = blockIdx.y;
    const int pxblk = blockIdx.x;
    const int t  = threadIdx.x;

    if (which == 3) {                          // weight-pack slice (r10 transform)
        const int idx = pxblk * 256 + t;       // 36864 threads for 16384 items
        if (idx < 16384) {
            const int sel = idx >> 12, local = idx & 4095;
            short8 s;
            if (sel == 0 || sel == 2) {        // [128][256] -> [256][128]
                const float* src = (sel == 0) ? w1a : w2a;
                short*       dst = (sel == 0) ? t1a : t2a;
                const int o = local >> 4, g = local & 15;
#pragma unroll
                for (int j = 0; j < 8; ++j) s[j] = f2bf(src[(g * 8 + j) * 256 + o]);
                *(short8*)(dst + (size_t)o * 128 + g * 8) = s;
            } else {                           // [256][128] -> [128][256]
                const float* src = (sel == 1) ? w1b : w2b;
                short*       dst = (sel == 1) ? t1b : t2b;
                const int o = local >> 5, g = local & 31;
#pragma unroll
                for (int j = 0; j < 8; ++j) s[j] = f2bf(src[(g * 8 + j) * 128 + o]);
                *(short8*)(dst + (size_t)o * 256 + g * 8) = s;
            }
        }
        return;
    }

    const int n0 = pxblk * PPT;
    const int c  = t & 127;
    const int ph = t >> 7;
    const float* x = (which == 0) ? xq : (which == 1) ? xk : xv;
    const float* w = (which == 0) ? wq : (which == 1) ? wk : wv;
    const float* b = (which == 0) ? bq : (which == 1) ? bk : bv;

#pragma unroll
    for (int it = 0; it < 8; ++it) {
        const int flat = it * 256 + t;
        const int cc = flat >> 4;
        const int p  = flat & 15;
        xsP[flat] = x[cc * NPIX + n0 + p];
    }
    if (which == 1)
        for (int u = t; u < 2 * NCL * CCH; u += 256) ls2[u] = 0.f;
    __syncthreads();

    float acc[8];
    const float bb = b[c];
#pragma unroll
    for (int p = 0; p < 8; ++p) acc[p] = bb;

#pragma unroll 4
    for (int in = 0; in < CCH; ++in) {
        const float wv_ = w[in * CCH + c];
        const float4 xa = *(const float4*)(xsP + in * PPT + ph * 8);
        const float4 xb = *(const float4*)(xsP + in * PPT + ph * 8 + 4);
        acc[0] = fmaf(xa.x, wv_, acc[0]); acc[1] = fmaf(xa.y, wv_, acc[1]);
        acc[2] = fmaf(xa.z, wv_, acc[2]); acc[3] = fmaf(xa.w, wv_, acc[3]);
        acc[4] = fmaf(xb.x, wv_, acc[4]); acc[5] = fmaf(xb.y, wv_, acc[5]);
        acc[6] = fmaf(xb.z, wv_, acc[6]); acc[7] = fmaf(xb.w, wv_, acc[7]);
    }

    const int nb = n0 + ph * 8;
    if (which == 0) {
#pragma unroll
        for (int p = 0; p < 8; ++p)
            qbf[(size_t)(nb + p) * CCH + c] = f2bf(acc[p] * QSCALE);
    } else if (which == 1) {
#pragma unroll
        for (int p = 0; p < 8; ++p)
            kbf[(size_t)(nb + p) * CCH + c] = f2bf(acc[p]);
        int lab8[8];
#pragma unroll
        for (int p = 0; p < 8; ++p) lab8[p] = labels[nb + p];
#pragma unroll
        for (int p = 0; p < 8; ++p)
            ls2[(ph * NCL + lab8[p]) * CCH + c] += acc[p];
        if (t < 32) {
            const int g2 = t >> 4, cl = t & 15;
            int cnt = 0;
#pragma unroll
            for (int p = 0; p < 8; ++p)
                cnt += (labels[n0 + g2 * 8 + p] == cl) ? 1 : 0;
            smls[t] = (float)cnt;
        }
        __syncthreads();
        for (int u = t; u < NCL * CCH; u += 256)
            cpart[(size_t)pxblk * 2048 + u] = ls2[u] + ls2[2048 + u];
        if (t < 16)
            denpart[pxblk * 16 + t] = smls[t] + smls[16 + t];
    } else {
#pragma unroll
        for (int p = 0; p < 8; ++p) vbuf[(size_t)(nb + p) * CCH + c] = acc[p];
        short8 s0;
#pragma unroll
        for (int p = 0; p < 8; ++p) s0[p] = f2bf(acc[p]);
        *(short8*)(vbfT + (size_t)c * NPIX + nb) = s0;
    }
}

// ---------------- Kernel 2: reduce partials -> bf16 centers ----------------
__global__ void centersB_kernel(const float* __restrict__ cpart,
                                const float* __restrict__ denpart,
                                short* __restrict__ cbf) {
    const int idx = blockIdx.x * 256 + threadIdx.x;   // 0..2047
    const int kk  = idx >> 7;
    float den = 0.f, s = 0.f;
    for (int b = 0; b < 144; ++b) den += denpart[b * 16 + kk];
    for (int b = 0; b < 144; ++b) s   += cpart[(size_t)b * 2048 + idx];
    cbf[idx] = f2bf(s / (den + 1e-6f));
}

// ---------------- Kernel 3: MFMA attention (r12-verified barrier-free body) ----
__global__ void __launch_bounds__(256, 4) attn_part_kernel(
        const short* __restrict__ qbf,  const short* __restrict__ kbf,
        const short* __restrict__ vbfT, const short* __restrict__ cbf,
        const int* __restrict__ labels, const float* __restrict__ pc,
        float* __restrict__ part_o, float* __restrict__ part_l) {
    __shared__ __align__(16) short Pl[NH][16 * 40];
    __shared__ __align__(16) float aclT[NH][16][16];
    __shared__ int   labl[KEYS];
    const int qt   = blockIdx.x;
    const int ks   = blockIdx.y;
    const int tid  = threadIdx.x;
    const int w    = tid >> 6;
    const int lane = tid & 63;
    const int quad = lane >> 4;
    const int lq   = lane & 15;
    const int i0   = qt * 16;
    const int j0   = ks * KEYS;

    for (int u = tid; u < KEYS / 4; u += 256)
        *(int4*)(labl + u * 4) = *(const int4*)(labels + j0 + u * 4);

    const short8 aq = *(const short8*)(qbf + (size_t)(i0 + lq) * CCH + w * HC + quad * 8);
    {
        const short8 bc = *(const short8*)(cbf + (size_t)lq * CCH + w * HC + quad * 8);
        f32x4 z = {0.f, 0.f, 0.f, 0.f};
        f32x4 acd = __builtin_amdgcn_mfma_f32_16x16x32_bf16(aq, bc, z, 0, 0, 0);
        *(f32x4*)(&aclT[w][lq][quad * 4]) = acd;   // [center][q-row], wave-private
    }
    int labi[4];
#pragma unroll
    for (int r = 0; r < 4; ++r) labi[r] = labels[i0 + quad * 4 + r];

    __syncthreads();   // labl ready

    const short* kp  = kbf  + (size_t)(j0 + lq) * CCH + w * HC + quad * 8;
    const short* vp  = vbfT + (size_t)(w * HC + lq) * NPIX + j0 + quad * 8;
    const float* pcp = pc   + (size_t)(i0 + quad * 4) * NPIX + j0 + lq;

    short8 k0A, k1A, v0A, v1A, k0B, k1B, v0B, v1B;
    float pcA[8], pcB[8];
    f32x4 accO0 = {0.f, 0.f, 0.f, 0.f};
    f32x4 accO1 = {0.f, 0.f, 0.f, 0.f};
    float lp[4] = {0.f, 0.f, 0.f, 0.f};

#define ISSUE(K0_, K1_, V0_, V1_, s) do {                                         \
        K0_ = *(const short8*)(kp + (size_t)(s) * 32 * CCH);                      \
        K1_ = *(const short8*)(kp + (size_t)((s) * 32 + 16) * CCH);               \
        V0_ = *(const short8*)(vp + (s) * 32);                                    \
        V1_ = *(const short8*)(vp + (size_t)16 * NPIX + (s) * 32);                \
    } while (0)

#define ISSUE_PC(dst, s) do {                                                     \
        _Pragma("unroll")                                                         \
        for (int r_ = 0; r_ < 4; ++r_) {                                          \
            dst[r_ * 2 + 0] = pcp[(size_t)r_ * NPIX + (s) * 32];                  \
            dst[r_ * 2 + 1] = pcp[(size_t)r_ * NPIX + (s) * 32 + 16];             \
        }                                                                         \
    } while (0)

#define COMPUTE(s, K0_, K1_, V0_, V1_, PCUSE) do {                                \
        _Pragma("unroll")                                                         \
        for (int kh = 0; kh < 2; ++kh) {                                          \
            const short8 bk = (kh == 0) ? K0_ : K1_;                              \
            f32x4 z = {0.f, 0.f, 0.f, 0.f};                                       \
            const f32x4 sv = __builtin_amdgcn_mfma_f32_16x16x32_bf16(aq, bk, z, 0, 0, 0);\
            const int slab = labl[(s) * 32 + kh * 16 + lq];                       \
            const f32x4 av4 = *(const f32x4*)(&aclT[w][slab][quad * 4]);          \
            _Pragma("unroll")                                                     \
            for (int r = 0; r < 4; ++r) {                                         \
                const float sc_ = (slab == labi[r]) ? sv[r] : av4[r] * PCUSE[r * 2 + kh];\
                const float p   = EXP2(sc_);                                      \
                lp[r] += p;                                                       \
                Pl[w][(quad * 4 + r) * 40 + kh * 16 + lq] = f2bf(p);              \
            }                                                                     \
        }                                                                         \
        const short8 ap = *(const short8*)(&Pl[w][lq * 40 + quad * 8]);           \
        accO0 = __builtin_amdgcn_mfma_f32_16x16x32_bf16(ap, V0_, accO0, 0, 0, 0); \
        accO1 = __builtin_amdgcn_mfma_f32_16x16x32_bf16(ap, V1_, accO1, 0, 0, 0); \
    } while (0)

    ISSUE(k0A, k1A, v0A, v1A, 0);
    ISSUE_PC(pcA, 0);
    for (int sb = 0; sb < NSTEP; sb += 2) {
        if (sb + 1 < NSTEP) { ISSUE(k0B, k1B, v0B, v1B, sb + 1); ISSUE_PC(pcB, sb + 1); }
        COMPUTE(sb, k0A, k1A, v0A, v1A, pcA);
        if (sb + 1 < NSTEP) {
            if (sb + 2 < NSTEP) { ISSUE(k0A, k1A, v0A, v1A, sb + 2); ISSUE_PC(pcA, sb + 2); }
            COMPUTE(sb + 1, k0B, k1B, v0B, v1B, pcB);
        }
    }
#undef ISSUE
#undef ISSUE_PC
#undef COMPUTE

#pragma unroll
    for (int r = 0; r < 4; ++r) {
        float v = lp[r];
        v += __shfl_xor(v, 1, 64);
        v += __shfl_xor(v, 2, 64);
        v += __shfl_xor(v, 4, 64);
        v += __shfl_xor(v, 8, 64);
        lp[r] = v;
    }
    if (lq == 0) {
#pragma unroll
        for (int r = 0; r < 4; ++r)
            part_l[((size_t)ks * NPIX + i0 + quad * 4 + r) * NH + w] = lp[r];
    }
#pragma unroll
    for (int r = 0; r < 4; ++r) {
        float* po = part_o + ((size_t)ks * NPIX + i0 + quad * 4 + r) * CCH + w * HC;
        po[lq]      = accO0[r];
        po[16 + lq] = accO1[r];
    }
}

// ---------------- Kernel 4: MFMA MLP chain, 16 px/block, 4 waves (r10 body) ----
// REVERT of r12's 16-wave re-tile: 256 threads, each wave owns 4 hidden tiles /
// 2 out tiles per stage (no idle waves, fewer barrier participants). r12 A/B
// suggests the 16-wave shape cost ~5us that cancelled the proj-fold gain.
#define XS 136   // 128+8 shorts, 16B-aligned rows
#define HS 264   // 256+8
__global__ void __launch_bounds__(256) mlp_mfma_kernel(
        const float* __restrict__ part_o, const float* __restrict__ part_l,
        const float* __restrict__ vbuf,
        const short* __restrict__ t1a, const float* __restrict__ b1a,
        const short* __restrict__ t1b, const float* __restrict__ b1b,
        const short* __restrict__ t2a, const float* __restrict__ b2a,
        const short* __restrict__ t2b, const float* __restrict__ b2b,
        float* __restrict__ outp) {
    __shared__ __align__(16) short xbf[16 * XS];    // x (attn out) bf16
    __shared__ __align__(16) short hbf[16 * HS];    // hidden bf16 (both MLPs)
    __shared__ __align__(16) short r1bf[16 * XS];   // rs1 bf16 (MLP2 input)
    __shared__ float fT[128 * 20];                  // final transposed (+pad)
    const int n0 = blockIdx.x * 16;
    const int t  = threadIdx.x;
    const int w  = t >> 6, lane = t & 63, quad = lane >> 4, lq = lane & 15;

    // stage: softmax-normalize attn partials -> bf16 x
    for (int u = t; u < 512; u += 256) {
        const int p = u >> 5, c4 = (u & 31) * 4, hh = c4 >> 5;
        float ls_ = 0.f;
#pragma unroll
        for (int ks = 0; ks < KSPLIT; ++ks)
            ls_ += part_l[((size_t)ks * NPIX + n0 + p) * NH + hh];
        float sx = 0.f, sy = 0.f, sz = 0.f, sw2 = 0.f;
#pragma unroll
        for (int ks = 0; ks < KSPLIT; ++ks) {
            const float4 v = *(const float4*)(part_o + ((size_t)ks * NPIX + n0 + p) * CCH + c4);
            sx += v.x; sy += v.y; sz += v.z; sw2 += v.w;
        }
        const float inv = 1.f / ls_;
        short4v s;
        s[0] = f2bf(sx * inv); s[1] = f2bf(sy * inv);
        s[2] = f2bf(sz * inv); s[3] = f2bf(sw2 * inv);
        *(short4v*)(xbf + p * XS + c4) = s;
    }
    __syncthreads();

    // MLP1 hidden: wave w -> outs [w*64, w*64+64), k=128
    {
        short8 a[4];
#pragma unroll
        for (int ks = 0; ks < 4; ++ks)
            a[ks] = *(const short8*)(xbf + lq * XS + ks * 32 + quad * 8);
#pragma unroll
        for (int tile = 0; tile < 4; ++tile) {
            const int out0 = w * 64 + tile * 16;
            f32x4 acc = {0.f, 0.f, 0.f, 0.f};
#pragma unroll
            for (int ks = 0; ks < 4; ++ks) {
                const short8 b = *(const short8*)(t1a + (size_t)(out0 + lq) * 128 + ks * 32 + quad * 8);
                acc = __builtin_amdgcn_mfma_f32_16x16x32_bf16(a[ks], b, acc, 0, 0, 0);
            }
            const float bb = b1a[out0 + lq];
#pragma unroll
            for (int r = 0; r < 4; ++r) {
                float v = acc[r] + bb;
                v = (v > 0.f) ? v : 0.01f * v;
                hbf[(quad * 4 + r) * HS + out0 + lq] = f2bf(v);
            }
        }
    }
    __syncthreads();

    // MLP1 out + residual v: wave w -> outs [w*32, w*32+32), k=256
    float rs1f[2][4];
    {
        short8 a[8];
#pragma unroll
        for (int ks = 0; ks < 8; ++ks)
            a[ks] = *(const short8*)(hbf + lq * HS + ks * 32 + quad * 8);
#pragma unroll
        for (int tile = 0; tile < 2; ++tile) {
            const int out0 = w * 32 + tile * 16;
            f32x4 acc = {0.f, 0.f, 0.f, 0.f};
#pragma unroll
            for (int ks = 0; ks < 8; ++ks) {
                const short8 b = *(const short8*)(t1b + (size_t)(out0 + lq) * 256 + ks * 32 + quad * 8);
                acc = __builtin_amdgcn_mfma_f32_16x16x32_bf16(a[ks], b, acc, 0, 0, 0);
            }
            const float bb = b1b[out0 + lq];
#pragma unroll
            for (int r = 0; r < 4; ++r) {
                const float v = acc[r] + bb +
                    vbuf[(size_t)(n0 + quad * 4 + r) * CCH + out0 + lq];
                rs1f[tile][r] = v;
                r1bf[(quad * 4 + r) * XS + out0 + lq] = f2bf(v);
            }
        }
    }
    __syncthreads();

    // MLP2 hidden
    {
        short8 a[4];
#pragma unroll
        for (int ks = 0; ks < 4; ++ks)
            a[ks] = *(const short8*)(r1bf + lq * XS + ks * 32 + quad * 8);
#pragma unroll
        for (int tile = 0; tile < 4; ++tile) {
            const int out0 = w * 64 + tile * 16;
            f32x4 acc = {0.f, 0.f, 0.f, 0.f};
#pragma unroll
            for (int ks = 0; ks < 4; ++ks) {
                const short8 b = *(const short8*)(t2a + (size_t)(out0 + lq) * 128 + ks * 32 + quad * 8);
                acc = __builtin_amdgcn_mfma_f32_16x16x32_bf16(a[ks], b, acc, 0, 0, 0);
            }
            const float bb = b2a[out0 + lq];
#pragma unroll
            for (int r = 0; r < 4; ++r) {
                float v = acc[r] + bb;
                v = (v > 0.f) ? v : 0.01f * v;
                hbf[(quad * 4 + r) * HS + out0 + lq] = f2bf(v);
            }
        }
    }
    __syncthreads();

    // MLP2 out + residual rs1 (regs) -> fT[c][px]
    {
        short8 a[8];
#pragma unroll
        for (int ks = 0; ks < 8; ++ks)
            a[ks] = *(const short8*)(hbf + lq * HS + ks * 32 + quad * 8);
#pragma unroll
        for (int tile = 0; tile < 2; ++tile) {
            const int out0 = w * 32 + tile * 16;
            f32x4 acc = {0.f, 0.f, 0.f, 0.f};
#pragma unroll
            for (int ks = 0; ks < 8; ++ks) {
                const short8 b = *(const short8*)(t2b + (size_t)(out0 + lq) * 256 + ks * 32 + quad * 8);
                acc = __builtin_amdgcn_mfma_f32_16x16x32_bf16(a[ks], b, acc, 0, 0, 0);
            }
            const float bb = b2b[out0 + lq];
#pragma unroll
            for (int r = 0; r < 4; ++r)
                fT[(out0 + lq) * 20 + quad * 4 + r] = acc[r] + bb + rs1f[tile][r];
        }
    }
    __syncthreads();

    // coalesced final store: out[c][n0..n0+16) as 4 x float4 per row
    for (int u = t; u < 512; u += 256) {
        const int row = u >> 2, seg = u & 3;
        const float4 v = *(const float4*)(fT + row * 20 + seg * 4);
        *(float4*)(outp + (size_t)row * NPIX + n0 + seg * 4) = v;
    }
}

extern "C" void kernel_launch(void* const* d_in, const int* in_sizes, int n_in,
                              void* d_out, int out_size, void* d_ws, size_t ws_size,
                              hipStream_t stream) {
    const float* q_img = (const float*)d_in[0];
    const float* k_img = (const float*)d_in[1];
    const float* v_img = (const float*)d_in[2];
    const float* pc    = (const float*)d_in[3];
    const int*   labels= (const int*)  d_in[4];
    const float* wq = (const float*)d_in[5];   const float* bq = (const float*)d_in[6];
    const float* wk = (const float*)d_in[7];   const float* bk = (const float*)d_in[8];
    const float* wv = (const float*)d_in[9];   const float* bv = (const float*)d_in[10];
    const float* w1a = (const float*)d_in[11]; const float* b1a = (const float*)d_in[12];
    const float* w1b = (const float*)d_in[13]; const float* b1b = (const float*)d_in[14];
    const float* w2a = (const float*)d_in[15]; const float* b2a = (const float*)d_in[16];
    const float* w2b = (const float*)d_in[17]; const float* b2b = (const float*)d_in[18];

    float* fw = (float*)d_ws;
    float* vbuf    = fw;                                   // [N][128]
    float* part_o  = vbuf + (size_t)NPIX * CCH;            // [8][N][128]
    float* part_l  = part_o + (size_t)KSPLIT * NPIX * CCH; // [8][N][4]
    float* cpart   = part_l + (size_t)KSPLIT * NPIX * NH;  // [144][2048]
    float* denpart = cpart + (size_t)144 * 2048;           // [144][16]
    short* t1a  = (short*)(denpart + 144 * 16);            // [256][128] bf16
    short* t1b  = t1a + 32768;                             // [128][256] bf16
    short* t2a  = t1b + 32768;                             // [256][128] bf16
    short* t2b  = t2a + 32768;                             // [128][256] bf16
    short* qbf  = t2b + 32768;                             // [N][128] bf16
    short* kbf  = qbf + (size_t)NPIX * CCH;                // [N][128] bf16
    short* vbfT = kbf + (size_t)NPIX * CCH;                // [128][N] bf16
    short* cbf  = vbfT + (size_t)NPIX * CCH;               // [16][128] bf16

    proj_kernel<<<dim3(144, 4), 256, 0, stream>>>(
        q_img, k_img, v_img, labels, wq, bq, wk, bk, wv, bv,
        w1a, w1b, w2a, w2b,
        qbf, kbf, vbuf, vbfT, cpart, denpart, t1a, t1b, t2a, t2b);
    centersB_kernel<<<8, 256, 0, stream>>>(cpart, denpart, cbf);
    attn_part_kernel<<<dim3(144, KSPLIT), 256, 0, stream>>>(
        qbf, kbf, vbfT, cbf, labels, pc, part_o, part_l);
    mlp_mfma_kernel<<<144, 256, 0, stream>>>(
        part_o, part_l, vbuf, t1a, b1a, t1b, b1b, t2a, b2a, t2b, b2b,
        (float*)d_out);
}

// Round 16
// 155.937 us; speedup vs baseline: 1.0239x; 1.0239x over previous
//
#include <hip/hip_runtime.h>
#include <hip/hip_bf16.h>
#include <math.h>

#define NPIX 2304
#define CCH  128
#define NH   4
#define HC   32
#define NCL  16
#define KSPLIT 8
#define KEYS 288
#define NSTEP 9
#define QSCALE 0.25503489f               // log2(e)/sqrt(32)

typedef __attribute__((ext_vector_type(8))) short short8;
typedef __attribute__((ext_vector_type(4))) short short4v;
typedef __attribute__((ext_vector_type(4))) float f32x4;

#if __has_builtin(__builtin_amdgcn_exp2f)
#define EXP2(x) __builtin_amdgcn_exp2f(x)
#else
#define EXP2(x) __expf((x) * 0.6931471805599453f)
#endif

static __device__ __forceinline__ short f2bf(float x) {
    __hip_bfloat16 b = __float2bfloat16(x);
    return *reinterpret_cast<short*>(&b);
}

// ---------------- Kernel 0: weight pack (separate dispatch: r14's fold raced --
// proj consumed tq/tk/tv written by sibling blocks of the SAME grid; block
// order is undefined. Dispatch boundary measured ~free in r12/r13 A/B.)
__global__ void __launch_bounds__(256) pack_w_kernel(
        const float* __restrict__ wq,  const float* __restrict__ wk,
        const float* __restrict__ wv,
        const float* __restrict__ w1a, const float* __restrict__ w1b,
        const float* __restrict__ w2a, const float* __restrict__ w2b,
        short* __restrict__ tq,  short* __restrict__ tk,
        short* __restrict__ tv,
        short* __restrict__ t1a, short* __restrict__ t1b,
        short* __restrict__ t2a, short* __restrict__ t2b) {
    const int idx = blockIdx.x * 256 + threadIdx.x;   // 0..22527
    if (idx < 16384) {                     // mlp packs (r10-verified)
        const int sel = idx >> 12, local = idx & 4095;
        short8 s;
        if (sel == 0 || sel == 2) {        // [128][256] -> [256][128]
            const float* src = (sel == 0) ? w1a : w2a;
            short*       dst = (sel == 0) ? t1a : t2a;
            const int o = local >> 4, g = local & 15;
#pragma unroll
            for (int j = 0; j < 8; ++j) s[j] = f2bf(src[(g * 8 + j) * 256 + o]);
            *(short8*)(dst + (size_t)o * 128 + g * 8) = s;
        } else {                           // [256][128] -> [128][256]
            const float* src = (sel == 1) ? w1b : w2b;
            short*       dst = (sel == 1) ? t1b : t2b;
            const int o = local >> 5, g = local & 31;
#pragma unroll
            for (int j = 0; j < 8; ++j) s[j] = f2bf(src[(g * 8 + j) * 128 + o]);
            *(short8*)(dst + (size_t)o * 256 + g * 8) = s;
        }
    } else if (idx < 22528) {              // proj packs [128][128] -> [out][in]
        const int i2 = idx - 16384;
        const int sel = i2 >> 11, local = i2 & 2047;
        const float* src = (sel == 0) ? wq : (sel == 1) ? wk : wv;
        short*       dst = (sel == 0) ? tq : (sel == 1) ? tk : tv;
        const int o = local >> 4, g = local & 15;
        short8 s;
#pragma unroll
        for (int j = 0; j < 8; ++j) s[j] = f2bf(src[(g * 8 + j) * 128 + o]);
        *(short8*)(dst + (size_t)o * 128 + g * 8) = s;
    }
}

// ---------------- Kernel 1: MFMA q/k/v projections + centersA ------------------
// proj was the last scalar-FMA matmul (1024 VALU FMA + 128 scalar weight loads
// per thread -- the exact structure that made mlp_chain cost 46us, fixed only
// by MFMA in r10). x staged transposed to bf16 LDS, weights [out][in] bf16,
// 8 MFMA/wave. Centers accumulate via an LDS f32 k-tile.
__global__ void __launch_bounds__(256) proj_kernel(
        const float* __restrict__ xq, const float* __restrict__ xk,
        const float* __restrict__ xv, const int* __restrict__ labels,
        const short* __restrict__ tq, const float* __restrict__ bq,
        const short* __restrict__ tk, const float* __restrict__ bk,
        const short* __restrict__ tv, const float* __restrict__ bv,
        short* __restrict__ qbf, short* __restrict__ kbf,
        float* __restrict__ vbuf, short* __restrict__ vbfT,
        float* __restrict__ cpart, float* __restrict__ denpart) {
    __shared__ __align__(16) short xbf[16 * 136];   // x^T bf16, padded rows
    __shared__ float kf[16 * 128];                   // k f32 tile (which==1)
    __shared__ float ls2[2 * NCL * CCH];             // 16 KB center partials
    __shared__ float smls[32];
    const int which = blockIdx.y;
    const int pxblk = blockIdx.x;
    const int t  = threadIdx.x;

    const int n0 = pxblk * 16;
    const int w    = t >> 6;
    const int lane = t & 63;
    const int quad = lane >> 4;
    const int lq   = lane & 15;
    const float* x  = (which == 0) ? xq : (which == 1) ? xk : xv;
    const short* wt = (which == 0) ? tq : (which == 1) ? tk : tv;
    const float* b  = (which == 0) ? bq : (which == 1) ? bk : bv;

    // stage x -> transposed bf16 LDS: xbf[p][cc]
#pragma unroll
    for (int it = 0; it < 8; ++it) {
        const int flat = it * 256 + t;         // 0..2047
        const int cc = flat >> 4, p = flat & 15;
        xbf[p * 136 + cc] = f2bf(x[cc * NPIX + n0 + p]);
    }
    if (which == 1)
        for (int u = t; u < 2 * NCL * CCH; u += 256) ls2[u] = 0.f;
    __syncthreads();

    // A-fragments: row = pixel lq, k = channel
    short8 a[4];
#pragma unroll
    for (int ks = 0; ks < 4; ++ks)
        a[ks] = *(const short8*)(xbf + lq * 136 + ks * 32 + quad * 8);

    // wave w -> out tiles w*32, w*32+16
    float ov[2][4];
#pragma unroll
    for (int tile = 0; tile < 2; ++tile) {
        const int out0 = w * 32 + tile * 16;
        f32x4 acc = {0.f, 0.f, 0.f, 0.f};
#pragma unroll
        for (int ks = 0; ks < 4; ++ks) {
            const short8 bw = *(const short8*)(wt + (size_t)(out0 + lq) * 128 + ks * 32 + quad * 8);
            acc = __builtin_amdgcn_mfma_f32_16x16x32_bf16(a[ks], bw, acc, 0, 0, 0);
        }
        const float bb = b[out0 + lq];
#pragma unroll
        for (int r = 0; r < 4; ++r) ov[tile][r] = acc[r] + bb;
    }

    // write outputs (C layout: row = n0+quad*4+r, col = out0+lq)
    if (which == 0) {
#pragma unroll
        for (int tile = 0; tile < 2; ++tile)
#pragma unroll
            for (int r = 0; r < 4; ++r)
                qbf[(size_t)(n0 + quad * 4 + r) * CCH + w * 32 + tile * 16 + lq] =
                    f2bf(ov[tile][r] * QSCALE);
    } else if (which == 1) {
#pragma unroll
        for (int tile = 0; tile < 2; ++tile)
#pragma unroll
            for (int r = 0; r < 4; ++r) {
                const float v = ov[tile][r];
                const int out0 = w * 32 + tile * 16;
                kbf[(size_t)(n0 + quad * 4 + r) * CCH + out0 + lq] = f2bf(v);
                kf[(quad * 4 + r) * 128 + out0 + lq] = v;
            }
        __syncthreads();
        // centers: thread owns column c for its px-half (race-free)
        const int c = t & 127, ph = t >> 7;
        int lab8[8];
#pragma unroll
        for (int p = 0; p < 8; ++p) lab8[p] = labels[n0 + ph * 8 + p];
#pragma unroll
        for (int p = 0; p < 8; ++p)
            ls2[(ph * NCL + lab8[p]) * CCH + c] += kf[(ph * 8 + p) * 128 + c];
        if (t < 32) {
            const int g2 = t >> 4, cl = t & 15;
            int cnt = 0;
#pragma unroll
            for (int p = 0; p < 8; ++p)
                cnt += (labels[n0 + g2 * 8 + p] == cl) ? 1 : 0;
            smls[t] = (float)cnt;
        }
        __syncthreads();
        for (int u = t; u < NCL * CCH; u += 256)
            cpart[(size_t)pxblk * 2048 + u] = ls2[u] + ls2[2048 + u];
        if (t < 16)
            denpart[pxblk * 16 + t] = smls[t] + smls[16 + t];
    } else {
#pragma unroll
        for (int tile = 0; tile < 2; ++tile)
#pragma unroll
            for (int r = 0; r < 4; ++r) {
                const float v = ov[tile][r];
                const int out0 = w * 32 + tile * 16;
                vbuf[(size_t)(n0 + quad * 4 + r) * CCH + out0 + lq] = v;
                vbfT[(size_t)(out0 + lq) * NPIX + n0 + quad * 4 + r] = f2bf(v);
            }
    }
}

// ---------------- Kernel 2: reduce partials -> bf16 centers ----------------
__global__ void centersB_kernel(const float* __restrict__ cpart,
                                const float* __restrict__ denpart,
                                short* __restrict__ cbf) {
    const int idx = blockIdx.x * 256 + threadIdx.x;   // 0..2047
    const int kk  = idx >> 7;
    float den = 0.f, s = 0.f;
    for (int b = 0; b < 144; ++b) den += denpart[b * 16 + kk];
    for (int b = 0; b < 144; ++b) s   += cpart[(size_t)b * 2048 + idx];
    cbf[idx] = f2bf(s / (den + 1e-6f));
}

// ---------------- Kernel 3: MFMA attention (r13-verified barrier-free body) ----
__global__ void __launch_bounds__(256, 4) attn_part_kernel(
        const short* __restrict__ qbf,  const short* __restrict__ kbf,
        const short* __restrict__ vbfT, const short* __restrict__ cbf,
        const int* __restrict__ labels, const float* __restrict__ pc,
        float* __restrict__ part_o, float* __restrict__ part_l) {
    __shared__ __align__(16) short Pl[NH][16 * 40];
    __shared__ __align__(16) float aclT[NH][16][16];
    __shared__ int   labl[KEYS];
    const int qt   = blockIdx.x;
    const int ks   = blockIdx.y;
    const int tid  = threadIdx.x;
    const int w    = tid >> 6;
    const int lane = tid & 63;
    const int quad = lane >> 4;
    const int lq   = lane & 15;
    const int i0   = qt * 16;
    const int j0   = ks * KEYS;

    for (int u = tid; u < KEYS / 4; u += 256)
        *(int4*)(labl + u * 4) = *(const int4*)(labels + j0 + u * 4);

    const short8 aq = *(const short8*)(qbf + (size_t)(i0 + lq) * CCH + w * HC + quad * 8);
    {
        const short8 bc = *(const short8*)(cbf + (size_t)lq * CCH + w * HC + quad * 8);
        f32x4 z = {0.f, 0.f, 0.f, 0.f};
        f32x4 acd = __builtin_amdgcn_mfma_f32_16x16x32_bf16(aq, bc, z, 0, 0, 0);
        *(f32x4*)(&aclT[w][lq][quad * 4]) = acd;   // [center][q-row], wave-private
    }
    int labi[4];
#pragma unroll
    for (int r = 0; r < 4; ++r) labi[r] = labels[i0 + quad * 4 + r];

    __syncthreads();   // labl ready

    const short* kp  = kbf  + (size_t)(j0 + lq) * CCH + w * HC + quad * 8;
    const short* vp  = vbfT + (size_t)(w * HC + lq) * NPIX + j0 + quad * 8;
    const float* pcp = pc   + (size_t)(i0 + quad * 4) * NPIX + j0 + lq;

    short8 k0A, k1A, v0A, v1A, k0B, k1B, v0B, v1B;
    float pcA[8], pcB[8];
    f32x4 accO0 = {0.f, 0.f, 0.f, 0.f};
    f32x4 accO1 = {0.f, 0.f, 0.f, 0.f};
    float lp[4] = {0.f, 0.f, 0.f, 0.f};

#define ISSUE(K0_, K1_, V0_, V1_, s) do {                                         \
        K0_ = *(const short8*)(kp + (size_t)(s) * 32 * CCH);                      \
        K1_ = *(const short8*)(kp + (size_t)((s) * 32 + 16) * CCH);               \
        V0_ = *(const short8*)(vp + (s) * 32);                                    \
        V1_ = *(const short8*)(vp + (size_t)16 * NPIX + (s) * 32);                \
    } while (0)

#define ISSUE_PC(dst, s) do {                                                     \
        _Pragma("unroll")                                                         \
        for (int r_ = 0; r_ < 4; ++r_) {                                          \
            dst[r_ * 2 + 0] = pcp[(size_t)r_ * NPIX + (s) * 32];                  \
            dst[r_ * 2 + 1] = pcp[(size_t)r_ * NPIX + (s) * 32 + 16];             \
        }                                                                         \
    } while (0)

#define COMPUTE(s, K0_, K1_, V0_, V1_, PCUSE) do {                                \
        _Pragma("unroll")                                                         \
        for (int kh = 0; kh < 2; ++kh) {                                          \
            const short8 bk = (kh == 0) ? K0_ : K1_;                              \
            f32x4 z = {0.f, 0.f, 0.f, 0.f};                                       \
            const f32x4 sv = __builtin_amdgcn_mfma_f32_16x16x32_bf16(aq, bk, z, 0, 0, 0);\
            const int slab = labl[(s) * 32 + kh * 16 + lq];                       \
            const f32x4 av4 = *(const f32x4*)(&aclT[w][slab][quad * 4]);          \
            _Pragma("unroll")                                                     \
            for (int r = 0; r < 4; ++r) {                                         \
                const float sc_ = (slab == labi[r]) ? sv[r] : av4[r] * PCUSE[r * 2 + kh];\
                const float p   = EXP2(sc_);                                      \
                lp[r] += p;                                                       \
                Pl[w][(quad * 4 + r) * 40 + kh * 16 + lq] = f2bf(p);              \
            }                                                                     \
        }                                                                         \
        const short8 ap = *(const short8*)(&Pl[w][lq * 40 + quad * 8]);           \
        accO0 = __builtin_amdgcn_mfma_f32_16x16x32_bf16(ap, V0_, accO0, 0, 0, 0); \
        accO1 = __builtin_amdgcn_mfma_f32_16x16x32_bf16(ap, V1_, accO1, 0, 0, 0); \
    } while (0)

    ISSUE(k0A, k1A, v0A, v1A, 0);
    ISSUE_PC(pcA, 0);
    for (int sb = 0; sb < NSTEP; sb += 2) {
        if (sb + 1 < NSTEP) { ISSUE(k0B, k1B, v0B, v1B, sb + 1); ISSUE_PC(pcB, sb + 1); }
        COMPUTE(sb, k0A, k1A, v0A, v1A, pcA);
        if (sb + 1 < NSTEP) {
            if (sb + 2 < NSTEP) { ISSUE(k0A, k1A, v0A, v1A, sb + 2); ISSUE_PC(pcA, sb + 2); }
            COMPUTE(sb + 1, k0B, k1B, v0B, v1B, pcB);
        }
    }
#undef ISSUE
#undef ISSUE_PC
#undef COMPUTE

#pragma unroll
    for (int r = 0; r < 4; ++r) {
        float v = lp[r];
        v += __shfl_xor(v, 1, 64);
        v += __shfl_xor(v, 2, 64);
        v += __shfl_xor(v, 4, 64);
        v += __shfl_xor(v, 8, 64);
        lp[r] = v;
    }
    if (lq == 0) {
#pragma unroll
        for (int r = 0; r < 4; ++r)
            part_l[((size_t)ks * NPIX + i0 + quad * 4 + r) * NH + w] = lp[r];
    }
#pragma unroll
    for (int r = 0; r < 4; ++r) {
        float* po = part_o + ((size_t)ks * NPIX + i0 + quad * 4 + r) * CCH + w * HC;
        po[lq]      = accO0[r];
        po[16 + lq] = accO1[r];
    }
}

// ---------------- Kernel 4: MFMA MLP chain (r13-verified, 256 thr) -------------
#define XS 136   // 128+8 shorts, 16B-aligned rows
#define HS 264   // 256+8
__global__ void __launch_bounds__(256) mlp_mfma_kernel(
        const float* __restrict__ part_o, const float* __restrict__ part_l,
        const float* __restrict__ vbuf,
        const short* __restrict__ t1a, const float* __restrict__ b1a,
        const short* __restrict__ t1b, const float* __restrict__ b1b,
        const short* __restrict__ t2a, const float* __restrict__ b2a,
        const short* __restrict__ t2b, const float* __restrict__ b2b,
        float* __restrict__ outp) {
    __shared__ __align__(16) short xbf[16 * XS];    // x (attn out) bf16
    __shared__ __align__(16) short hbf[16 * HS];    // hidden bf16 (both MLPs)
    __shared__ __align__(16) short r1bf[16 * XS];   // rs1 bf16 (MLP2 input)
    __shared__ float fT[128 * 20];                  // final transposed (+pad)
    const int n0 = blockIdx.x * 16;
    const int t  = threadIdx.x;
    const int w  = t >> 6, lane = t & 63, quad = lane >> 4, lq = lane & 15;

    // stage: softmax-normalize attn partials -> bf16 x
    for (int u = t; u < 512; u += 256) {
        const int p = u >> 5, c4 = (u & 31) * 4, hh = c4 >> 5;
        float ls_ = 0.f;
#pragma unroll
        for (int ks = 0; ks < KSPLIT; ++ks)
            ls_ += part_l[((size_t)ks * NPIX + n0 + p) * NH + hh];
        float sx = 0.f, sy = 0.f, sz = 0.f, sw2 = 0.f;
#pragma unroll
        for (int ks = 0; ks < KSPLIT; ++ks) {
            const float4 v = *(const float4*)(part_o + ((size_t)ks * NPIX + n0 + p) * CCH + c4);
            sx += v.x; sy += v.y; sz += v.z; sw2 += v.w;
        }
        const float inv = 1.f / ls_;
        short4v s;
        s[0] = f2bf(sx * inv); s[1] = f2bf(sy * inv);
        s[2] = f2bf(sz * inv); s[3] = f2bf(sw2 * inv);
        *(short4v*)(xbf + p * XS + c4) = s;
    }
    __syncthreads();

    // MLP1 hidden: wave w -> outs [w*64, w*64+64), k=128
    {
        short8 a[4];
#pragma unroll
        for (int ks = 0; ks < 4; ++ks)
            a[ks] = *(const short8*)(xbf + lq * XS + ks * 32 + quad * 8);
#pragma unroll
        for (int tile = 0; tile < 4; ++tile) {
            const int out0 = w * 64 + tile * 16;
            f32x4 acc = {0.f, 0.f, 0.f, 0.f};
#pragma unroll
            for (int ks = 0; ks < 4; ++ks) {
                const short8 b = *(const short8*)(t1a + (size_t)(out0 + lq) * 128 + ks * 32 + quad * 8);
                acc = __builtin_amdgcn_mfma_f32_16x16x32_bf16(a[ks], b, acc, 0, 0, 0);
            }
            const float bb = b1a[out0 + lq];
#pragma unroll
            for (int r = 0; r < 4; ++r) {
                float v = acc[r] + bb;
                v = (v > 0.f) ? v : 0.01f * v;
                hbf[(quad * 4 + r) * HS + out0 + lq] = f2bf(v);
            }
        }
    }
    __syncthreads();

    // MLP1 out + residual v: wave w -> outs [w*32, w*32+32), k=256
    float rs1f[2][4];
    {
        short8 a[8];
#pragma unroll
        for (int ks = 0; ks < 8; ++ks)
            a[ks] = *(const short8*)(hbf + lq * HS + ks * 32 + quad * 8);
#pragma unroll
        for (int tile = 0; tile < 2; ++tile) {
            const int out0 = w * 32 + tile * 16;
            f32x4 acc = {0.f, 0.f, 0.f, 0.f};
#pragma unroll
            for (int ks = 0; ks < 8; ++ks) {
                const short8 b = *(const short8*)(t1b + (size_t)(out0 + lq) * 256 + ks * 32 + quad * 8);
                acc = __builtin_amdgcn_mfma_f32_16x16x32_bf16(a[ks], b, acc, 0, 0, 0);
            }
            const float bb = b1b[out0 + lq];
#pragma unroll
            for (int r = 0; r < 4; ++r) {
                const float v = acc[r] + bb +
                    vbuf[(size_t)(n0 + quad * 4 + r) * CCH + out0 + lq];
                rs1f[tile][r] = v;
                r1bf[(quad * 4 + r) * XS + out0 + lq] = f2bf(v);
            }
        }
    }
    __syncthreads();

    // MLP2 hidden
    {
        short8 a[4];
#pragma unroll
        for (int ks = 0; ks < 4; ++ks)
            a[ks] = *(const short8*)(r1bf + lq * XS + ks * 32 + quad * 8);
#pragma unroll
        for (int tile = 0; tile < 4; ++tile) {
            const int out0 = w * 64 + tile * 16;
            f32x4 acc = {0.f, 0.f, 0.f, 0.f};
#pragma unroll
            for (int ks = 0; ks < 4; ++ks) {
                const short8 b = *(const short8*)(t2a + (size_t)(out0 + lq) * 128 + ks * 32 + quad * 8);
                acc = __builtin_amdgcn_mfma_f32_16x16x32_bf16(a[ks], b, acc, 0, 0, 0);
            }
            const float bb = b2a[out0 + lq];
#pragma unroll
            for (int r = 0; r < 4; ++r) {
                float v = acc[r] + bb;
                v = (v > 0.f) ? v : 0.01f * v;
                hbf[(quad * 4 + r) * HS + out0 + lq] = f2bf(v);
            }
        }
    }
    __syncthreads();

    // MLP2 out + residual rs1 (regs) -> fT[c][px]
    {
        short8 a[8];
#pragma unroll
        for (int ks = 0; ks < 8; ++ks)
            a[ks] = *(const short8*)(hbf + lq * HS + ks * 32 + quad * 8);
#pragma unroll
        for (int tile = 0; tile < 2; ++tile) {
            const int out0 = w * 32 + tile * 16;
            f32x4 acc = {0.f, 0.f, 0.f, 0.f};
#pragma unroll
            for (int ks = 0; ks < 8; ++ks) {
                const short8 b = *(const short8*)(t2b + (size_t)(out0 + lq) * 256 + ks * 32 + quad * 8);
                acc = __builtin_amdgcn_mfma_f32_16x16x32_bf16(a[ks], b, acc, 0, 0, 0);
            }
            const float bb = b2b[out0 + lq];
#pragma unroll
            for (int r = 0; r < 4; ++r)
                fT[(out0 + lq) * 20 + quad * 4 + r] = acc[r] + bb + rs1f[tile][r];
        }
    }
    __syncthreads();

    // coalesced final store: out[c][n0..n0+16) as 4 x float4 per row
    for (int u = t; u < 512; u += 256) {
        const int row = u >> 2, seg = u & 3;
        const float4 v = *(const float4*)(fT + row * 20 + seg * 4);
        *(float4*)(outp + (size_t)row * NPIX + n0 + seg * 4) = v;
    }
}

extern "C" void kernel_launch(void* const* d_in, const int* in_sizes, int n_in,
                              void* d_out, int out_size, void* d_ws, size_t ws_size,
                              hipStream_t stream) {
    const float* q_img = (const float*)d_in[0];
    const float* k_img = (const float*)d_in[1];
    const float* v_img = (const float*)d_in[2];
    const float* pc    = (const float*)d_in[3];
    const int*   labels= (const int*)  d_in[4];
    const float* wq = (const float*)d_in[5];   const float* bq = (const float*)d_in[6];
    const float* wk = (const float*)d_in[7];   const float* bk = (const float*)d_in[8];
    const float* wv = (const float*)d_in[9];   const float* bv = (const float*)d_in[10];
    const float* w1a = (const float*)d_in[11]; const float* b1a = (const float*)d_in[12];
    const float* w1b = (const float*)d_in[13]; const float* b1b = (const float*)d_in[14];
    const float* w2a = (const float*)d_in[15]; const float* b2a = (const float*)d_in[16];
    const float* w2b = (const float*)d_in[17]; const float* b2b = (const float*)d_in[18];

    float* fw = (float*)d_ws;
    float* vbuf    = fw;                                   // [N][128]
    float* part_o  = vbuf + (size_t)NPIX * CCH;            // [8][N][128]
    float* part_l  = part_o + (size_t)KSPLIT * NPIX * CCH; // [8][N][4]
    float* cpart   = part_l + (size_t)KSPLIT * NPIX * NH;  // [144][2048]
    float* denpart = cpart + (size_t)144 * 2048;           // [144][16]
    short* t1a  = (short*)(denpart + 144 * 16);            // [256][128] bf16
    short* t1b  = t1a + 32768;                             // [128][256] bf16
    short* t2a  = t1b + 32768;                             // [256][128] bf16
    short* t2b  = t2a + 32768;                             // [128][256] bf16
    short* tq   = t2b + 32768;                             // [128][128] bf16
    short* tk   = tq + 16384;                              // [128][128] bf16
    short* tv   = tk + 16384;                              // [128][128] bf16
    short* qbf  = tv + 16384;                              // [N][128] bf16
    short* kbf  = qbf + (size_t)NPIX * CCH;                // [N][128] bf16
    short* vbfT = kbf + (size_t)NPIX * CCH;                // [128][N] bf16
    short* cbf  = vbfT + (size_t)NPIX * CCH;               // [16][128] bf16

    pack_w_kernel<<<88, 256, 0, stream>>>(
        wq, wk, wv, w1a, w1b, w2a, w2b, tq, tk, tv, t1a, t1b, t2a, t2b);
    proj_kernel<<<dim3(144, 3), 256, 0, stream>>>(
        q_img, k_img, v_img, labels, tq, bq, tk, bk, tv, bv,
        qbf, kbf, vbuf, vbfT, cpart, denpart);
    centersB_kernel<<<8, 256, 0, stream>>>(cpart, denpart, cbf);
    attn_part_kernel<<<dim3(144, KSPLIT), 256, 0, stream>>>(
        qbf, kbf, vbfT, cbf, labels, pc, part_o, part_l);
    mlp_mfma_kernel<<<144, 256, 0, stream>>>(
        part_o, part_l, vbuf, t1a, b1a, t1b, b1b, t2a, b2a, t2b, b2b,
        (float*)d_out);
}

// Round 17
// 153.457 us; speedup vs baseline: 1.0404x; 1.0162x over previous
//
#include <hip/hip_runtime.h>
#include <hip/hip_bf16.h>
#include <math.h>

#define NPIX 2304
#define CCH  128
#define NH   4
#define HC   32
#define NCL  16
#define KSPLIT 8
#define KEYS 288
#define NSTEP 9
#define QSCALE 0.25503489f               // log2(e)/sqrt(32)

typedef __attribute__((ext_vector_type(8))) short short8;
typedef __attribute__((ext_vector_type(4))) short short4v;
typedef __attribute__((ext_vector_type(4))) float f32x4;

#if __has_builtin(__builtin_amdgcn_exp2f)
#define EXP2(x) __builtin_amdgcn_exp2f(x)
#else
#define EXP2(x) __expf((x) * 0.6931471805599453f)
#endif

static __device__ __forceinline__ short f2bf(float x) {
    __hip_bfloat16 b = __float2bfloat16(x);
    return *reinterpret_cast<short*>(&b);
}

// ---------------- Kernel 0: weight pack (r16-verified) -------------------------
__global__ void __launch_bounds__(256) pack_w_kernel(
        const float* __restrict__ wq,  const float* __restrict__ wk,
        const float* __restrict__ wv,
        const float* __restrict__ w1a, const float* __restrict__ w1b,
        const float* __restrict__ w2a, const float* __restrict__ w2b,
        short* __restrict__ tq,  short* __restrict__ tk,
        short* __restrict__ tv,
        short* __restrict__ t1a, short* __restrict__ t1b,
        short* __restrict__ t2a, short* __restrict__ t2b) {
    const int idx = blockIdx.x * 256 + threadIdx.x;   // 0..22527
    if (idx < 16384) {                     // mlp packs (r10-verified)
        const int sel = idx >> 12, local = idx & 4095;
        short8 s;
        if (sel == 0 || sel == 2) {        // [128][256] -> [256][128]
            const float* src = (sel == 0) ? w1a : w2a;
            short*       dst = (sel == 0) ? t1a : t2a;
            const int o = local >> 4, g = local & 15;
#pragma unroll
            for (int j = 0; j < 8; ++j) s[j] = f2bf(src[(g * 8 + j) * 256 + o]);
            *(short8*)(dst + (size_t)o * 128 + g * 8) = s;
        } else {                           // [256][128] -> [128][256]
            const float* src = (sel == 1) ? w1b : w2b;
            short*       dst = (sel == 1) ? t1b : t2b;
            const int o = local >> 5, g = local & 31;
#pragma unroll
            for (int j = 0; j < 8; ++j) s[j] = f2bf(src[(g * 8 + j) * 128 + o]);
            *(short8*)(dst + (size_t)o * 256 + g * 8) = s;
        }
    } else if (idx < 22528) {              // proj packs [128][128] -> [out][in]
        const int i2 = idx - 16384;
        const int sel = i2 >> 11, local = i2 & 2047;
        const float* src = (sel == 0) ? wq : (sel == 1) ? wk : wv;
        short*       dst = (sel == 0) ? tq : (sel == 1) ? tk : tv;
        const int o = local >> 4, g = local & 15;
        short8 s;
#pragma unroll
        for (int j = 0; j < 8; ++j) s[j] = f2bf(src[(g * 8 + j) * 128 + o]);
        *(short8*)(dst + (size_t)o * 128 + g * 8) = s;
    }
}

// ---------------- Kernel 1: MFMA q/k/v projections + centersA (r16-verified) ---
__global__ void __launch_bounds__(256) proj_kernel(
        const float* __restrict__ xq, const float* __restrict__ xk,
        const float* __restrict__ xv, const int* __restrict__ labels,
        const short* __restrict__ tq, const float* __restrict__ bq,
        const short* __restrict__ tk, const float* __restrict__ bk,
        const short* __restrict__ tv, const float* __restrict__ bv,
        short* __restrict__ qbf, short* __restrict__ kbf,
        float* __restrict__ vbuf, short* __restrict__ vbfT,
        float* __restrict__ cpart, float* __restrict__ denpart) {
    __shared__ __align__(16) short xbf[16 * 136];   // x^T bf16, padded rows
    __shared__ float kf[16 * 128];                   // k f32 tile (which==1)
    __shared__ float ls2[2 * NCL * CCH];             // 16 KB center partials
    __shared__ float smls[32];
    const int which = blockIdx.y;
    const int pxblk = blockIdx.x;
    const int t  = threadIdx.x;

    const int n0 = pxblk * 16;
    const int w    = t >> 6;
    const int lane = t & 63;
    const int quad = lane >> 4;
    const int lq   = lane & 15;
    const float* x  = (which == 0) ? xq : (which == 1) ? xk : xv;
    const short* wt = (which == 0) ? tq : (which == 1) ? tk : tv;
    const float* b  = (which == 0) ? bq : (which == 1) ? bk : bv;

    // stage x -> transposed bf16 LDS: xbf[p][cc]
#pragma unroll
    for (int it = 0; it < 8; ++it) {
        const int flat = it * 256 + t;         // 0..2047
        const int cc = flat >> 4, p = flat & 15;
        xbf[p * 136 + cc] = f2bf(x[cc * NPIX + n0 + p]);
    }
    if (which == 1)
        for (int u = t; u < 2 * NCL * CCH; u += 256) ls2[u] = 0.f;
    __syncthreads();

    // A-fragments: row = pixel lq, k = channel
    short8 a[4];
#pragma unroll
    for (int ks = 0; ks < 4; ++ks)
        a[ks] = *(const short8*)(xbf + lq * 136 + ks * 32 + quad * 8);

    // wave w -> out tiles w*32, w*32+16
    float ov[2][4];
#pragma unroll
    for (int tile = 0; tile < 2; ++tile) {
        const int out0 = w * 32 + tile * 16;
        f32x4 acc = {0.f, 0.f, 0.f, 0.f};
#pragma unroll
        for (int ks = 0; ks < 4; ++ks) {
            const short8 bw = *(const short8*)(wt + (size_t)(out0 + lq) * 128 + ks * 32 + quad * 8);
            acc = __builtin_amdgcn_mfma_f32_16x16x32_bf16(a[ks], bw, acc, 0, 0, 0);
        }
        const float bb = b[out0 + lq];
#pragma unroll
        for (int r = 0; r < 4; ++r) ov[tile][r] = acc[r] + bb;
    }

    // write outputs (C layout: row = n0+quad*4+r, col = out0+lq)
    if (which == 0) {
#pragma unroll
        for (int tile = 0; tile < 2; ++tile)
#pragma unroll
            for (int r = 0; r < 4; ++r)
                qbf[(size_t)(n0 + quad * 4 + r) * CCH + w * 32 + tile * 16 + lq] =
                    f2bf(ov[tile][r] * QSCALE);
    } else if (which == 1) {
#pragma unroll
        for (int tile = 0; tile < 2; ++tile)
#pragma unroll
            for (int r = 0; r < 4; ++r) {
                const float v = ov[tile][r];
                const int out0 = w * 32 + tile * 16;
                kbf[(size_t)(n0 + quad * 4 + r) * CCH + out0 + lq] = f2bf(v);
                kf[(quad * 4 + r) * 128 + out0 + lq] = v;
            }
        __syncthreads();
        // centers: thread owns column c for its px-half (race-free)
        const int c = t & 127, ph = t >> 7;
        int lab8[8];
#pragma unroll
        for (int p = 0; p < 8; ++p) lab8[p] = labels[n0 + ph * 8 + p];
#pragma unroll
        for (int p = 0; p < 8; ++p)
            ls2[(ph * NCL + lab8[p]) * CCH + c] += kf[(ph * 8 + p) * 128 + c];
        if (t < 32) {
            const int g2 = t >> 4, cl = t & 15;
            int cnt = 0;
#pragma unroll
            for (int p = 0; p < 8; ++p)
                cnt += (labels[n0 + g2 * 8 + p] == cl) ? 1 : 0;
            smls[t] = (float)cnt;
        }
        __syncthreads();
        for (int u = t; u < NCL * CCH; u += 256)
            cpart[(size_t)pxblk * 2048 + u] = ls2[u] + ls2[2048 + u];
        if (t < 16)
            denpart[pxblk * 16 + t] = smls[t] + smls[16 + t];
    } else {
#pragma unroll
        for (int tile = 0; tile < 2; ++tile)
#pragma unroll
            for (int r = 0; r < 4; ++r) {
                const float v = ov[tile][r];
                const int out0 = w * 32 + tile * 16;
                vbuf[(size_t)(n0 + quad * 4 + r) * CCH + out0 + lq] = v;
                vbfT[(size_t)(out0 + lq) * NPIX + n0 + quad * 4 + r] = f2bf(v);
            }
    }
}

// ---------------- Kernel 2: reduce partials -> bf16 centers ----------------
__global__ void centersB_kernel(const float* __restrict__ cpart,
                                const float* __restrict__ denpart,
                                short* __restrict__ cbf) {
    const int idx = blockIdx.x * 256 + threadIdx.x;   // 0..2047
    const int kk  = idx >> 7;
    float den = 0.f, s = 0.f;
    for (int b = 0; b < 144; ++b) den += denpart[b * 16 + kk];
    for (int b = 0; b < 144; ++b) s   += cpart[(size_t)b * 2048 + idx];
    cbf[idx] = f2bf(s / (den + 1e-6f));
}

// ---------------- Kernel 3: MFMA attention, PV pipelined by one step -----------
// r16 body + structural fix: the per-step serial chain QK->softmax->LDS P
// round-trip->PV exposed latency every step. Now PV(s-1) consumes Pl[(s-1)&1]
// (written last iteration, no wait) while QK(s) fills Pl[s&1]. V lives in a
// register triple-buffer (fully unrolled loop -> compile-time slot indices).
__global__ void __launch_bounds__(256, 4) attn_part_kernel(
        const short* __restrict__ qbf,  const short* __restrict__ kbf,
        const short* __restrict__ vbfT, const short* __restrict__ cbf,
        const int* __restrict__ labels, const float* __restrict__ pc,
        float* __restrict__ part_o, float* __restrict__ part_l) {
    __shared__ __align__(16) short Pl[NH][2][16 * 40];   // double P buffer/wave
    __shared__ __align__(16) float aclT[NH][16][16];
    __shared__ int   labl[KEYS];
    const int qt   = blockIdx.x;
    const int ks   = blockIdx.y;
    const int tid  = threadIdx.x;
    const int w    = tid >> 6;
    const int lane = tid & 63;
    const int quad = lane >> 4;
    const int lq   = lane & 15;
    const int i0   = qt * 16;
    const int j0   = ks * KEYS;

    for (int u = tid; u < KEYS / 4; u += 256)
        *(int4*)(labl + u * 4) = *(const int4*)(labels + j0 + u * 4);

    const short8 aq = *(const short8*)(qbf + (size_t)(i0 + lq) * CCH + w * HC + quad * 8);
    {
        const short8 bc = *(const short8*)(cbf + (size_t)lq * CCH + w * HC + quad * 8);
        f32x4 z = {0.f, 0.f, 0.f, 0.f};
        f32x4 acd = __builtin_amdgcn_mfma_f32_16x16x32_bf16(aq, bc, z, 0, 0, 0);
        *(f32x4*)(&aclT[w][lq][quad * 4]) = acd;   // [center][q-row], wave-private
    }
    int labi[4];
#pragma unroll
    for (int r = 0; r < 4; ++r) labi[r] = labels[i0 + quad * 4 + r];

    __syncthreads();   // labl ready

    const short* kp  = kbf  + (size_t)(j0 + lq) * CCH + w * HC + quad * 8;
    const short* vp  = vbfT + (size_t)(w * HC + lq) * NPIX + j0 + quad * 8;
    const float* pcp = pc   + (size_t)(i0 + quad * 4) * NPIX + j0 + lq;

    short8 kA0, kA1, kB0, kB1;
    short8 v0s[3], v1s[3];            // V ring (indices compile-time via unroll)
    float pcA[8], pcB[8];
    f32x4 accO0 = {0.f, 0.f, 0.f, 0.f};
    f32x4 accO1 = {0.f, 0.f, 0.f, 0.f};
    float lp[4] = {0.f, 0.f, 0.f, 0.f};

#define ISSUE_K(K0_, K1_, s) do {                                                 \
        K0_ = *(const short8*)(kp + (size_t)(s) * 32 * CCH);                      \
        K1_ = *(const short8*)(kp + (size_t)((s) * 32 + 16) * CCH);               \
    } while (0)

#define ISSUE_V(slot, s) do {                                                     \
        v0s[slot] = *(const short8*)(vp + (s) * 32);                              \
        v1s[slot] = *(const short8*)(vp + (size_t)16 * NPIX + (s) * 32);          \
    } while (0)

#define ISSUE_PC(dst, s) do {                                                     \
        _Pragma("unroll")                                                         \
        for (int r_ = 0; r_ < 4; ++r_) {                                          \
            dst[r_ * 2 + 0] = pcp[(size_t)r_ * NPIX + (s) * 32];                  \
            dst[r_ * 2 + 1] = pcp[(size_t)r_ * NPIX + (s) * 32 + 16];             \
        }                                                                         \
    } while (0)

#define QK(s, K0_, K1_, PCUSE, pb) do {                                           \
        _Pragma("unroll")                                                         \
        for (int kh = 0; kh < 2; ++kh) {                                          \
            const short8 bk = (kh == 0) ? K0_ : K1_;                              \
            f32x4 z = {0.f, 0.f, 0.f, 0.f};                                       \
            const f32x4 sv = __builtin_amdgcn_mfma_f32_16x16x32_bf16(aq, bk, z, 0, 0, 0);\
            const int slab = labl[(s) * 32 + kh * 16 + lq];                       \
            const f32x4 av4 = *(const f32x4*)(&aclT[w][slab][quad * 4]);          \
            _Pragma("unroll")                                                     \
            for (int r = 0; r < 4; ++r) {                                         \
                const float sc_ = (slab == labi[r]) ? sv[r] : av4[r] * PCUSE[r * 2 + kh];\
                const float p   = EXP2(sc_);                                      \
                lp[r] += p;                                                       \
                Pl[w][pb][(quad * 4 + r) * 40 + kh * 16 + lq] = f2bf(p);          \
            }                                                                     \
        }                                                                         \
    } while (0)

#define PV(pb, vslot) do {                                                        \
        const short8 ap = *(const short8*)(&Pl[w][pb][lq * 40 + quad * 8]);       \
        accO0 = __builtin_amdgcn_mfma_f32_16x16x32_bf16(ap, v0s[vslot], accO0, 0, 0, 0);\
        accO1 = __builtin_amdgcn_mfma_f32_16x16x32_bf16(ap, v1s[vslot], accO1, 0, 0, 0);\
    } while (0)

    // prologue: step-0 operands
    ISSUE_K(kA0, kA1, 0);
    ISSUE_PC(pcA, 0);
    ISSUE_V(0, 0);
#pragma unroll
    for (int sb = 0; sb < NSTEP; ++sb) {
        if (sb + 1 < NSTEP) {                       // issue next step's operands
            if ((sb & 1) == 0) { ISSUE_K(kB0, kB1, sb + 1); ISSUE_PC(pcB, sb + 1); }
            else               { ISSUE_K(kA0, kA1, sb + 1); ISSUE_PC(pcA, sb + 1); }
            ISSUE_V((sb + 1) % 3, sb + 1);
        }
        if ((sb & 1) == 0) QK(sb, kA0, kA1, pcA, 0);
        else               QK(sb, kB0, kB1, pcB, 1);
        if (sb > 0) PV((sb - 1) & 1, (sb - 1) % 3); // P from last iter: no wait
    }
    PV((NSTEP - 1) & 1, (NSTEP - 1) % 3);           // epilogue PV(8)
#undef ISSUE_K
#undef ISSUE_V
#undef ISSUE_PC
#undef QK
#undef PV

#pragma unroll
    for (int r = 0; r < 4; ++r) {
        float v = lp[r];
        v += __shfl_xor(v, 1, 64);
        v += __shfl_xor(v, 2, 64);
        v += __shfl_xor(v, 4, 64);
        v += __shfl_xor(v, 8, 64);
        lp[r] = v;
    }
    if (lq == 0) {
#pragma unroll
        for (int r = 0; r < 4; ++r)
            part_l[((size_t)ks * NPIX + i0 + quad * 4 + r) * NH + w] = lp[r];
    }
#pragma unroll
    for (int r = 0; r < 4; ++r) {
        float* po = part_o + ((size_t)ks * NPIX + i0 + quad * 4 + r) * CCH + w * HC;
        po[lq]      = accO0[r];
        po[16 + lq] = accO1[r];
    }
}

// ---------------- Kernel 4: MFMA MLP chain (r16-verified, 256 thr) -------------
#define XS 136   // 128+8 shorts, 16B-aligned rows
#define HS 264   // 256+8
__global__ void __launch_bounds__(256) mlp_mfma_kernel(
        const float* __restrict__ part_o, const float* __restrict__ part_l,
        const float* __restrict__ vbuf,
        const short* __restrict__ t1a, const float* __restrict__ b1a,
        const short* __restrict__ t1b, const float* __restrict__ b1b,
        const short* __restrict__ t2a, const float* __restrict__ b2a,
        const short* __restrict__ t2b, const float* __restrict__ b2b,
        float* __restrict__ outp) {
    __shared__ __align__(16) short xbf[16 * XS];    // x (attn out) bf16
    __shared__ __align__(16) short hbf[16 * HS];    // hidden bf16 (both MLPs)
    __shared__ __align__(16) short r1bf[16 * XS];   // rs1 bf16 (MLP2 input)
    __shared__ float fT[128 * 20];                  // final transposed (+pad)
    const int n0 = blockIdx.x * 16;
    const int t  = threadIdx.x;
    const int w  = t >> 6, lane = t & 63, quad = lane >> 4, lq = lane & 15;

    // stage: softmax-normalize attn partials -> bf16 x
    for (int u = t; u < 512; u += 256) {
        const int p = u >> 5, c4 = (u & 31) * 4, hh = c4 >> 5;
        float ls_ = 0.f;
#pragma unroll
        for (int ks = 0; ks < KSPLIT; ++ks)
            ls_ += part_l[((size_t)ks * NPIX + n0 + p) * NH + hh];
        float sx = 0.f, sy = 0.f, sz = 0.f, sw2 = 0.f;
#pragma unroll
        for (int ks = 0; ks < KSPLIT; ++ks) {
            const float4 v = *(const float4*)(part_o + ((size_t)ks * NPIX + n0 + p) * CCH + c4);
            sx += v.x; sy += v.y; sz += v.z; sw2 += v.w;
        }
        const float inv = 1.f / ls_;
        short4v s;
        s[0] = f2bf(sx * inv); s[1] = f2bf(sy * inv);
        s[2] = f2bf(sz * inv); s[3] = f2bf(sw2 * inv);
        *(short4v*)(xbf + p * XS + c4) = s;
    }
    __syncthreads();

    // MLP1 hidden: wave w -> outs [w*64, w*64+64), k=128
    {
        short8 a[4];
#pragma unroll
        for (int ks = 0; ks < 4; ++ks)
            a[ks] = *(const short8*)(xbf + lq * XS + ks * 32 + quad * 8);
#pragma unroll
        for (int tile = 0; tile < 4; ++tile) {
            const int out0 = w * 64 + tile * 16;
            f32x4 acc = {0.f, 0.f, 0.f, 0.f};
#pragma unroll
            for (int ks = 0; ks < 4; ++ks) {
                const short8 b = *(const short8*)(t1a + (size_t)(out0 + lq) * 128 + ks * 32 + quad * 8);
                acc = __builtin_amdgcn_mfma_f32_16x16x32_bf16(a[ks], b, acc, 0, 0, 0);
            }
            const float bb = b1a[out0 + lq];
#pragma unroll
            for (int r = 0; r < 4; ++r) {
                float v = acc[r] + bb;
                v = (v > 0.f) ? v : 0.01f * v;
                hbf[(quad * 4 + r) * HS + out0 + lq] = f2bf(v);
            }
        }
    }
    __syncthreads();

    // MLP1 out + residual v: wave w -> outs [w*32, w*32+32), k=256
    float rs1f[2][4];
    {
        short8 a[8];
#pragma unroll
        for (int ks = 0; ks < 8; ++ks)
            a[ks] = *(const short8*)(hbf + lq * HS + ks * 32 + quad * 8);
#pragma unroll
        for (int tile = 0; tile < 2; ++tile) {
            const int out0 = w * 32 + tile * 16;
            f32x4 acc = {0.f, 0.f, 0.f, 0.f};
#pragma unroll
            for (int ks = 0; ks < 8; ++ks) {
                const short8 b = *(const short8*)(t1b + (size_t)(out0 + lq) * 256 + ks * 32 + quad * 8);
                acc = __builtin_amdgcn_mfma_f32_16x16x32_bf16(a[ks], b, acc, 0, 0, 0);
            }
            const float bb = b1b[out0 + lq];
#pragma unroll
            for (int r = 0; r < 4; ++r) {
                const float v = acc[r] + bb +
                    vbuf[(size_t)(n0 + quad * 4 + r) * CCH + out0 + lq];
                rs1f[tile][r] = v;
                r1bf[(quad * 4 + r) * XS + out0 + lq] = f2bf(v);
            }
        }
    }
    __syncthreads();

    // MLP2 hidden
    {
        short8 a[4];
#pragma unroll
        for (int ks = 0; ks < 4; ++ks)
            a[ks] = *(const short8*)(r1bf + lq * XS + ks * 32 + quad * 8);
#pragma unroll
        for (int tile = 0; tile < 4; ++tile) {
            const int out0 = w * 64 + tile * 16;
            f32x4 acc = {0.f, 0.f, 0.f, 0.f};
#pragma unroll
            for (int ks = 0; ks < 4; ++ks) {
                const short8 b = *(const short8*)(t2a + (size_t)(out0 + lq) * 128 + ks * 32 + quad * 8);
                acc = __builtin_amdgcn_mfma_f32_16x16x32_bf16(a[ks], b, acc, 0, 0, 0);
            }
            const float bb = b2a[out0 + lq];
#pragma unroll
            for (int r = 0; r < 4; ++r) {
                float v = acc[r] + bb;
                v = (v > 0.f) ? v : 0.01f * v;
                hbf[(quad * 4 + r) * HS + out0 + lq] = f2bf(v);
            }
        }
    }
    __syncthreads();

    // MLP2 out + residual rs1 (regs) -> fT[c][px]
    {
        short8 a[8];
#pragma unroll
        for (int ks = 0; ks < 8; ++ks)
            a[ks] = *(const short8*)(hbf + lq * HS + ks * 32 + quad * 8);
#pragma unroll
        for (int tile = 0; tile < 2; ++tile) {
            const int out0 = w * 32 + tile * 16;
            f32x4 acc = {0.f, 0.f, 0.f, 0.f};
#pragma unroll
            for (int ks = 0; ks < 8; ++ks) {
                const short8 b = *(const short8*)(t2b + (size_t)(out0 + lq) * 256 + ks * 32 + quad * 8);
                acc = __builtin_amdgcn_mfma_f32_16x16x32_bf16(a[ks], b, acc, 0, 0, 0);
            }
            const float bb = b2b[out0 + lq];
#pragma unroll
            for (int r = 0; r < 4; ++r)
                fT[(out0 + lq) * 20 + quad * 4 + r] = acc[r] + bb + rs1f[tile][r];
        }
    }
    __syncthreads();

    // coalesced final store: out[c][n0..n0+16) as 4 x float4 per row
    for (int u = t; u < 512; u += 256) {
        const int row = u >> 2, seg = u & 3;
        const float4 v = *(const float4*)(fT + row * 20 + seg * 4);
        *(float4*)(outp + (size_t)row * NPIX + n0 + seg * 4) = v;
    }
}

extern "C" void kernel_launch(void* const* d_in, const int* in_sizes, int n_in,
                              void* d_out, int out_size, void* d_ws, size_t ws_size,
                              hipStream_t stream) {
    const float* q_img = (const float*)d_in[0];
    const float* k_img = (const float*)d_in[1];
    const float* v_img = (const float*)d_in[2];
    const float* pc    = (const float*)d_in[3];
    const int*   labels= (const int*)  d_in[4];
    const float* wq = (const float*)d_in[5];   const float* bq = (const float*)d_in[6];
    const float* wk = (const float*)d_in[7];   const float* bk = (const float*)d_in[8];
    const float* wv = (const float*)d_in[9];   const float* bv = (const float*)d_in[10];
    const float* w1a = (const float*)d_in[11]; const float* b1a = (const float*)d_in[12];
    const float* w1b = (const float*)d_in[13]; const float* b1b = (const float*)d_in[14];
    const float* w2a = (const float*)d_in[15]; const float* b2a = (const float*)d_in[16];
    const float* w2b = (const float*)d_in[17]; const float* b2b = (const float*)d_in[18];

    float* fw = (float*)d_ws;
    float* vbuf    = fw;                                   // [N][128]
    float* part_o  = vbuf + (size_t)NPIX * CCH;            // [8][N][128]
    float* part_l  = part_o + (size_t)KSPLIT * NPIX * CCH; // [8][N][4]
    float* cpart   = part_l + (size_t)KSPLIT * NPIX * NH;  // [144][2048]
    float* denpart = cpart + (size_t)144 * 2048;           // [144][16]
    short* t1a  = (short*)(denpart + 144 * 16);            // [256][128] bf16
    short* t1b  = t1a + 32768;                             // [128][256] bf16
    short* t2a  = t1b + 32768;                             // [256][128] bf16
    short* t2b  = t2a + 32768;                             // [128][256] bf16
    short* tq   = t2b + 32768;                             // [128][128] bf16
    short* tk   = tq + 16384;                              // [128][128] bf16
    short* tv   = tk + 16384;                              // [128][128] bf16
    short* qbf  = tv + 16384;                              // [N][128] bf16
    short* kbf  = qbf + (size_t)NPIX * CCH;                // [N][128] bf16
    short* vbfT = kbf + (size_t)NPIX * CCH;                // [128][N] bf16
    short* cbf  = vbfT + (size_t)NPIX * CCH;               // [16][128] bf16

    pack_w_kernel<<<88, 256, 0, stream>>>(
        wq, wk, wv, w1a, w1b, w2a, w2b, tq, tk, tv, t1a, t1b, t2a, t2b);
    proj_kernel<<<dim3(144, 3), 256, 0, stream>>>(
        q_img, k_img, v_img, labels, tq, bq, tk, bk, tv, bv,
        qbf, kbf, vbuf, vbfT, cpart, denpart);
    centersB_kernel<<<8, 256, 0, stream>>>(cpart, denpart, cbf);
    attn_part_kernel<<<dim3(144, KSPLIT), 256, 0, stream>>>(
        qbf, kbf, vbfT, cbf, labels, pc, part_o, part_l);
    mlp_mfma_kernel<<<144, 256, 0, stream>>>(
        part_o, part_l, vbuf, t1a, b1a, t1b, b1b, t2a, b2a, t2b, b2b,
        (float*)d_out);
}